// Round 3
// baseline (1214.992 us; speedup 1.0000x reference)
//
#include <hip/hip_runtime.h>
#include <stdint.h>

// GeometricBilinearLayer: B=32,N=1024,Cin=64,Cout=64,H=32, PGA(3,0,1)
// All tensors float32 (per reference dtypes).
#define BN 32768
#define TPW 2   // tokens per wave

// ---------- compile-time Clifford tables (mirror reference _blade_mul) ----------
constexpr int IDX2MASK[16] = {0,1,2,4,8,3,5,9,6,10,12,7,11,13,14,15};
constexpr int MASK2IDX[16] = {0,1,2,5,3,6,8,11,4,7,9,12,10,13,14,15};

struct MulRes { float s; int idx; };

constexpr MulRes blade_mul(int ia, int ib) {
  int arr[8] = {0,0,0,0,0,0,0,0}; int n = 0;
  for (int e = 0; e < 4; ++e) if ((IDX2MASK[ia] >> e) & 1) arr[n++] = e;
  for (int e = 0; e < 4; ++e) if ((IDX2MASK[ib] >> e) & 1) arr[n++] = e;
  float sign = 1.0f;
  bool sw = true;
  while (sw) {
    sw = false;
    for (int j = 0; j + 1 < n; ++j)
      if (arr[j] > arr[j+1]) { int t = arr[j]; arr[j] = arr[j+1]; arr[j+1] = t; sign = -sign; sw = true; }
  }
  int mask = 0; int j = 0;
  while (j < n) {
    if (j + 1 < n && arr[j] == arr[j+1]) { if (arr[j] == 0) sign = 0.0f; j += 2; }  // e0^2 = 0
    else { mask |= 1 << arr[j]; ++j; }
  }
  return MulRes{sign, MASK2IDX[mask]};
}

constexpr float dual_sign(int i) {   // blade_i ^ comp(blade_i) = s * e0123
  return blade_mul(i, MASK2IDX[15 ^ IDX2MASK[i]]).s;
}

struct Tab { float s[16][16]; int k[16][16]; };

constexpr Tab make_gp() {
  Tab t{};
  for (int i = 0; i < 16; ++i)
    for (int j = 0; j < 16; ++j) { MulRes r = blade_mul(i, j); t.s[i][j] = r.s; t.k[i][j] = r.idx; }
  return t;
}

constexpr Tab make_join() {   // join = undual(dual(x) ^ dual(y))
  Tab t{};
  for (int i = 0; i < 16; ++i)
    for (int j = 0; j < 16; ++j) {
      int ma = 15 ^ IDX2MASK[i], mb = 15 ^ IDX2MASK[j];
      if (ma & mb) { t.s[i][j] = 0.0f; t.k[i][j] = 0; continue; }
      int ia = MASK2IDX[ma], ib = MASK2IDX[mb];
      MulRes w = blade_mul(ia, ib);                      // wedge of complements (disjoint)
      int kk = MASK2IDX[15 ^ IDX2MASK[w.idx]];           // undual
      t.s[i][j] = dual_sign(i) * dual_sign(j) * w.s * dual_sign(kk);
      t.k[i][j] = kk;
    }
  return t;
}

constexpr Tab GPT = make_gp();
constexpr Tab JNT = make_join();
constexpr int GRADE[16] = {0,1,1,1,1,2,2,2,2,2,2,3,3,3,3,4};

// ---------- module-scope repacked weights (f32) ----------
// g_wpre[c][i][12]: [0..4]=wX[g], [5..9]=wY[g], pad; c<32 -> prod ch c, c>=32 -> join ch c-32
// g_wfin[o][cc][8]: [0..4]=w_final[g][o][cc], pad
__device__ float g_wpre[64 * 64 * 12];   // 192 KB
__device__ float g_wfin[64 * 64 * 8];    // 128 KB

__global__ void repack_weights(const float* __restrict__ wpx, const float* __restrict__ wpy,
                               const float* __restrict__ wjx, const float* __restrict__ wjy,
                               const float* __restrict__ wf) {
  int t = blockIdx.x * blockDim.x + threadIdx.x;   // 0..4095 -> (c, i)
  if (t >= 64 * 64) return;
  int c = t >> 6, i = t & 63;
  const float* wx = (c < 32) ? wpx : wjx;
  const float* wy = (c < 32) ? wpy : wjy;
  int cc = c & 31;
  #pragma unroll
  for (int g = 0; g < 5; ++g) {
    g_wpre[t*12 + g]     = wx[g*2048 + cc*64 + i];
    g_wpre[t*12 + 5 + g] = wy[g*2048 + cc*64 + i];
  }
  g_wpre[t*12 + 10] = 0.f; g_wpre[t*12 + 11] = 0.f;
  #pragma unroll
  for (int g = 0; g < 5; ++g) g_wfin[t*8 + g] = wf[g*4096 + c*64 + i];   // (c,i)=(o,cc)
  #pragma unroll
  for (int q = 5; q < 8; ++q) g_wfin[t*8 + q] = 0.f;
}

// ---------- main fused kernel: 1 block = 4 waves = 8 tokens ----------
__global__ __launch_bounds__(256) void gbl_kernel(
    const float* __restrict__ x,     // [BN][64][16]
    const float* __restrict__ ref,   // [BN][16]
    float* __restrict__ out)         // [BN][64][16]
{
  __shared__ float feats[4][TPW][64][20];   // 80B rows: 16B aligned, bank-spread
  const int tid = threadIdx.x;
  const int w = tid >> 6;
  const int c = tid & 63;                    // lane = feats channel
  const int tbase = blockIdx.x * (4 * TPW) + w * TPW;

  float ax[TPW][16], ay[TPW][16];
  #pragma unroll
  for (int t = 0; t < TPW; ++t)
    #pragma unroll
    for (int k = 0; k < 16; ++k) { ax[t][k] = 0.f; ay[t][k] = 0.f; }

  // Phase 1: pre-equilins (px,py for c<32; jx,jy for c>=32)
  #pragma unroll 2
  for (int i = 0; i < 64; ++i) {
    const float4* wb = (const float4*)(g_wpre + (c*64 + i)*12);
    float4 w0 = wb[0], w1 = wb[1], w2 = wb[2];
    float wX[5] = {w0.x, w0.y, w0.z, w0.w, w1.x};
    float wY[5] = {w1.y, w1.z, w1.w, w2.x, w2.y};
    #pragma unroll
    for (int t = 0; t < TPW; ++t) {
      const float4* xb = (const float4*)(x + (size_t)(tbase + t)*1024 + i*16);
      float4 x0 = xb[0], x1 = xb[1], x2 = xb[2], x3 = xb[3];
      float xv[16] = {x0.x,x0.y,x0.z,x0.w, x1.x,x1.y,x1.z,x1.w,
                      x2.x,x2.y,x2.z,x2.w, x3.x,x3.y,x3.z,x3.w};
      #pragma unroll
      for (int k = 0; k < 16; ++k) {
        ax[t][k] = fmaf(xv[k], wX[GRADE[k]], ax[t][k]);
        ay[t][k] = fmaf(xv[k], wY[GRADE[k]], ay[t][k]);
      }
    }
  }

  // Phase 2: bilinear (GP for c<32, JOIN*ref_pss for c>=32) -> LDS feats
  #pragma unroll
  for (int t = 0; t < TPW; ++t) {
    float pr[16];
    #pragma unroll
    for (int k = 0; k < 16; ++k) pr[k] = 0.f;
    if (c < 32) {
      #pragma unroll
      for (int i = 0; i < 16; ++i)
        #pragma unroll
        for (int j = 0; j < 16; ++j) {
          float s = GPT.s[i][j];
          if (s != 0.f) {
            float a = (s < 0.f) ? -ax[t][i] : ax[t][i];
            pr[GPT.k[i][j]] = fmaf(a, ay[t][j], pr[GPT.k[i][j]]);
          }
        }
    } else {
      #pragma unroll
      for (int i = 0; i < 16; ++i)
        #pragma unroll
        for (int j = 0; j < 16; ++j) {
          float s = JNT.s[i][j];
          if (s != 0.f) {
            float a = (s < 0.f) ? -ax[t][i] : ax[t][i];
            pr[JNT.k[i][j]] = fmaf(a, ay[t][j], pr[JNT.k[i][j]]);
          }
        }
      float rv = ref[(size_t)(tbase + t)*16 + 15];
      #pragma unroll
      for (int k = 0; k < 16; ++k) pr[k] *= rv;
    }
    #pragma unroll
    for (int k = 0; k < 16; ++k) feats[w][t][c][k] = pr[k];
  }
  __syncthreads();

  // Phase 3: final equilin, lane = output channel o = c
  float acc[TPW][16];
  #pragma unroll
  for (int t = 0; t < TPW; ++t)
    #pragma unroll
    for (int k = 0; k < 16; ++k) acc[t][k] = 0.f;
  #pragma unroll 4
  for (int cc = 0; cc < 64; ++cc) {
    const float4* fwp = (const float4*)(g_wfin + (c*64 + cc)*8);
    float4 fw = fwp[0];
    float wg4 = g_wfin[(c*64 + cc)*8 + 4];
    float wg[5] = {fw.x, fw.y, fw.z, fw.w, wg4};
    #pragma unroll
    for (int t = 0; t < TPW; ++t) {
      const float4* fp = (const float4*)&feats[w][t][cc][0];
      float4 f0 = fp[0], f1 = fp[1], f2 = fp[2], f3 = fp[3];
      float fv[16] = {f0.x,f0.y,f0.z,f0.w, f1.x,f1.y,f1.z,f1.w,
                      f2.x,f2.y,f2.z,f2.w, f3.x,f3.y,f3.z,f3.w};
      #pragma unroll
      for (int k = 0; k < 16; ++k)
        acc[t][k] = fmaf(fv[k], wg[GRADE[k]], acc[t][k]);
    }
  }

  // Store: out[t][o=c][0..15], 64B per lane, float4 x4
  #pragma unroll
  for (int t = 0; t < TPW; ++t) {
    float4* op = (float4*)(out + (size_t)(tbase + t)*1024 + c*16);
    op[0] = make_float4(acc[t][0],  acc[t][1],  acc[t][2],  acc[t][3]);
    op[1] = make_float4(acc[t][4],  acc[t][5],  acc[t][6],  acc[t][7]);
    op[2] = make_float4(acc[t][8],  acc[t][9],  acc[t][10], acc[t][11]);
    op[3] = make_float4(acc[t][12], acc[t][13], acc[t][14], acc[t][15]);
  }
}

extern "C" void kernel_launch(void* const* d_in, const int* in_sizes, int n_in,
                              void* d_out, int out_size, void* d_ws, size_t ws_size,
                              hipStream_t stream) {
  const float* x   = (const float*)d_in[0];
  const float* ref = (const float*)d_in[1];
  const float* wpx = (const float*)d_in[2];
  const float* wpy = (const float*)d_in[3];
  const float* wjx = (const float*)d_in[4];
  const float* wjy = (const float*)d_in[5];
  const float* wfi = (const float*)d_in[6];

  repack_weights<<<16, 256, 0, stream>>>(wpx, wpy, wjx, wjy, wfi);
  gbl_kernel<<<BN / (4*TPW), 256, 0, stream>>>(x, ref, (float*)d_out);
}

// Round 4
// 283.938 us; speedup vs baseline: 4.2791x; 4.2791x over previous
//
#include <hip/hip_runtime.h>
#include <stdint.h>

// GeometricBilinearLayer: B=32,N=1024,Cin=64,Cout=64,H=32, PGA(3,0,1). f32 I/O.
// R4: MFMA restructure. 1 block = 4 waves = one 16-token tile.
//   wave w: branch=w>>1 (prod/join), nt=w&1 (H-half) for stage-A; o-ntile=w for final.

#define BN 32768
#define PLANE 1160          // shorts per blade-plane: 16 tok * 72 + 8 pad (2320 B)
#define TROW 72             // shorts per token row (64 i/cc + 8 pad = 144 B)

typedef __attribute__((ext_vector_type(8))) short short8;   // 8 bf16 = 4 VGPR (guide-verified frag type)
typedef __attribute__((ext_vector_type(4))) float f32x4;

#define MFMA_BF16 __builtin_amdgcn_mfma_f32_16x16x32_bf16

// ---------- compile-time Clifford tables (verified by R3 pass) ----------
constexpr int IDX2MASK[16] = {0,1,2,4,8,3,5,9,6,10,12,7,11,13,14,15};
constexpr int MASK2IDX[16] = {0,1,2,5,3,6,8,11,4,7,9,12,10,13,14,15};

struct MulRes { float s; int idx; };

constexpr MulRes blade_mul(int ia, int ib) {
  int arr[8] = {0,0,0,0,0,0,0,0}; int n = 0;
  for (int e = 0; e < 4; ++e) if ((IDX2MASK[ia] >> e) & 1) arr[n++] = e;
  for (int e = 0; e < 4; ++e) if ((IDX2MASK[ib] >> e) & 1) arr[n++] = e;
  float sign = 1.0f;
  bool sw = true;
  while (sw) {
    sw = false;
    for (int j = 0; j + 1 < n; ++j)
      if (arr[j] > arr[j+1]) { int t = arr[j]; arr[j] = arr[j+1]; arr[j+1] = t; sign = -sign; sw = true; }
  }
  int mask = 0; int j = 0;
  while (j < n) {
    if (j + 1 < n && arr[j] == arr[j+1]) { if (arr[j] == 0) sign = 0.0f; j += 2; }  // e0^2 = 0
    else { mask |= 1 << arr[j]; ++j; }
  }
  return MulRes{sign, MASK2IDX[mask]};
}

constexpr float dual_sign(int i) {
  return blade_mul(i, MASK2IDX[15 ^ IDX2MASK[i]]).s;
}

struct Tab { float s[16][16]; int k[16][16]; };

constexpr Tab make_gp() {
  Tab t{};
  for (int i = 0; i < 16; ++i)
    for (int j = 0; j < 16; ++j) { MulRes r = blade_mul(i, j); t.s[i][j] = r.s; t.k[i][j] = r.idx; }
  return t;
}

constexpr Tab make_join() {
  Tab t{};
  for (int i = 0; i < 16; ++i)
    for (int j = 0; j < 16; ++j) {
      int ma = 15 ^ IDX2MASK[i], mb = 15 ^ IDX2MASK[j];
      if (ma & mb) { t.s[i][j] = 0.0f; t.k[i][j] = 0; continue; }
      int ia = MASK2IDX[ma], ib = MASK2IDX[mb];
      MulRes w = blade_mul(ia, ib);
      int kk = MASK2IDX[15 ^ IDX2MASK[w.idx]];
      t.s[i][j] = dual_sign(i) * dual_sign(j) * w.s * dual_sign(kk);
      t.k[i][j] = kk;
    }
  return t;
}

constexpr Tab GPT = make_gp();
constexpr Tab JNT = make_join();
constexpr int GRADE[16] = {0,1,1,1,1,2,2,2,2,2,2,3,3,3,3,4};

// per-output-blade regrouped bilinear tables (same terms, k-major)
struct KTab { int cnt[16]; int ti[16][16]; int tj[16][16]; float ts[16][16]; };
constexpr KTab make_ktab(const Tab& t) {
  KTab b{};
  for (int i = 0; i < 16; ++i)
    for (int j = 0; j < 16; ++j) {
      float s = t.s[i][j];
      if (s != 0.f) { int k = t.k[i][j]; int m = b.cnt[k]; b.cnt[k] = m + 1;
                      b.ti[k][m] = i; b.tj[k][m] = j; b.ts[k][m] = s; }
    }
  return b;
}
constexpr KTab GPK = make_ktab(GPT);   // 192 terms, 12 per k
constexpr KTab JNK = make_ktab(JNT);   // 81 terms, <=16 per k

__device__ __forceinline__ uint32_t f2bf(float f){
  union{float f; uint32_t i;} v; v.f = f;
  return (v.i + 0x7fffu + ((v.i >> 16) & 1u)) >> 16;   // RNE
}

// ---------- bf16 weight tables (module-scope; rewritten every launch) ----------
// g_wpre_b[(br*2+set)][g][c(32)][i(64)] = concat(wpX,wpY,wjX,wjY) cast to bf16
// g_wfin_b[g][o(64)][cc(64)]            = w_final cast to bf16
__device__ short g_wpre_b[4 * 5 * 32 * 64];   // 40960 shorts
__device__ short g_wfin_b[5 * 64 * 64];       // 20480 shorts

__global__ void cast_weights(const float* __restrict__ wpx, const float* __restrict__ wpy,
                             const float* __restrict__ wjx, const float* __restrict__ wjy,
                             const float* __restrict__ wf) {
  int idx = blockIdx.x * 256 + threadIdx.x;
  if (idx < 40960) {
    int which = idx / 10240, r = idx % 10240;
    const float* src = (which == 0) ? wpx : (which == 1) ? wpy : (which == 2) ? wjx : wjy;
    g_wpre_b[idx] = (short)f2bf(src[r]);
  } else if (idx < 40960 + 20480) {
    int r = idx - 40960;
    g_wfin_b[r] = (short)f2bf(wf[r]);
  }
}

// ---------- main kernel ----------
__global__ __launch_bounds__(256, 2) void gbl_kernel(
    const float* __restrict__ x,     // [BN][64][16]
    const float* __restrict__ ref,   // [BN][16]
    float* __restrict__ out)         // [BN][64][16]
{
  // one buffer, two lives: xT[blade][tok][i] bf16, then fT[blade][tok][cc] bf16
  __shared__ __align__(16) short ldsb[16 * PLANE];   // 37120 B

  const int tid  = threadIdx.x;
  const int w    = tid >> 6;        // wave 0..3
  const int lane = tid & 63;
  const int n    = lane & 15;       // MFMA free-dim lane index (t-row for A, c/o-col for B)
  const int q    = lane >> 4;       // quad
  const int t0   = blockIdx.x * 16;

  // ---- Phase 0: stage x-tile -> xT (transposed, bf16) ----
  {
    const int k  = tid & 15;          // blade
    const int tt = tid >> 4;          // token row 0..15
    const float* xr = x + (size_t)(t0 + tt) * 1024 + k;   // stride 16 floats over i
    #pragma unroll
    for (int ib = 0; ib < 8; ++ib) {
      float v[8];
      #pragma unroll
      for (int j = 0; j < 8; ++j) v[j] = xr[(ib * 8 + j) * 16];
      short8 p;
      #pragma unroll
      for (int j = 0; j < 8; ++j) p[j] = (short)f2bf(v[j]);
      *(short8*)&ldsb[k * PLANE + tt * TROW + ib * 8] = p;
    }
  }
  __syncthreads();

  // ---- Phase 1: stage-A pre-equilins via MFMA ----
  // wave w: branch br = w>>1 (0=prod,1=join), nt = w&1 (c-half). c_global = w*16 + n.
  const int br = w >> 1, nt = w & 1;

  float px[16][4], py[16][4];

  // set X
  {
    short8 B[5][2];
    #pragma unroll
    for (int g = 0; g < 5; ++g)
      #pragma unroll
      for (int ks = 0; ks < 2; ++ks)
        B[g][ks] = *(short8*)&g_wpre_b[(((br * 2 + 0) * 5 + g) * 32 + nt * 16 + n) * 64 + ks * 32 + q * 8];
    #pragma unroll
    for (int kb = 0; kb < 16; ++kb) {
      short8 a0 = *(short8*)&ldsb[kb * PLANE + n * TROW + 0  + q * 8];
      short8 a1 = *(short8*)&ldsb[kb * PLANE + n * TROW + 32 + q * 8];
      f32x4 acc = {0.f, 0.f, 0.f, 0.f};
      acc = MFMA_BF16(a0, B[GRADE[kb]][0], acc, 0, 0, 0);
      acc = MFMA_BF16(a1, B[GRADE[kb]][1], acc, 0, 0, 0);
      #pragma unroll
      for (int r = 0; r < 4; ++r) px[kb][r] = acc[r];
    }
  }
  // set Y
  {
    short8 B[5][2];
    #pragma unroll
    for (int g = 0; g < 5; ++g)
      #pragma unroll
      for (int ks = 0; ks < 2; ++ks)
        B[g][ks] = *(short8*)&g_wpre_b[(((br * 2 + 1) * 5 + g) * 32 + nt * 16 + n) * 64 + ks * 32 + q * 8];
    #pragma unroll
    for (int kb = 0; kb < 16; ++kb) {
      short8 a0 = *(short8*)&ldsb[kb * PLANE + n * TROW + 0  + q * 8];
      short8 a1 = *(short8*)&ldsb[kb * PLANE + n * TROW + 32 + q * 8];
      f32x4 acc = {0.f, 0.f, 0.f, 0.f};
      acc = MFMA_BF16(a0, B[GRADE[kb]][0], acc, 0, 0, 0);
      acc = MFMA_BF16(a1, B[GRADE[kb]][1], acc, 0, 0, 0);
      #pragma unroll
      for (int r = 0; r < 4; ++r) py[kb][r] = acc[r];
    }
  }

  __syncthreads();   // all xT reads done; ldsb becomes fT

  // ---- Phase 2: in-register bilinear -> fT (bf16) ----
  // lane holds px/py for c = w*16 + n, tokens t = 4q + r (r = reg)
  {
    float rv[4];
    if (br == 1) {
      #pragma unroll
      for (int r = 0; r < 4; ++r) rv[r] = ref[(size_t)(t0 + 4 * q + r) * 16 + 15];
    }
    const int cg = w * 16 + n;
    #pragma unroll
    for (int k = 0; k < 16; ++k) {
      float a[4] = {0.f, 0.f, 0.f, 0.f};
      if (br == 0) {
        #pragma unroll
        for (int m = 0; m < 16; ++m) {
          if (m < GPK.cnt[k]) {
            const int i = GPK.ti[k][m], j = GPK.tj[k][m];
            const bool neg = GPK.ts[k][m] < 0.f;
            #pragma unroll
            for (int r = 0; r < 4; ++r)
              a[r] = fmaf(neg ? -px[i][r] : px[i][r], py[j][r], a[r]);
          }
        }
      } else {
        #pragma unroll
        for (int m = 0; m < 16; ++m) {
          if (m < JNK.cnt[k]) {
            const int i = JNK.ti[k][m], j = JNK.tj[k][m];
            const bool neg = JNK.ts[k][m] < 0.f;
            #pragma unroll
            for (int r = 0; r < 4; ++r)
              a[r] = fmaf(neg ? -px[i][r] : px[i][r], py[j][r], a[r]);
          }
        }
        #pragma unroll
        for (int r = 0; r < 4; ++r) a[r] *= rv[r];
      }
      #pragma unroll
      for (int r = 0; r < 4; ++r)
        ldsb[k * PLANE + (4 * q + r) * TROW + cg] = (short)f2bf(a[r]);
    }
  }
  __syncthreads();

  // ---- Phase 3: final equilin via MFMA; wave w owns o in [w*16, w*16+16) ----
  {
    short8 BF[5][2];
    #pragma unroll
    for (int g = 0; g < 5; ++g)
      #pragma unroll
      for (int ks = 0; ks < 2; ++ks)
        BF[g][ks] = *(short8*)&g_wfin_b[(g * 64 + w * 16 + n) * 64 + ks * 32 + q * 8];

    f32x4 D[16];
    #pragma unroll
    for (int kb = 0; kb < 16; ++kb) {
      short8 a0 = *(short8*)&ldsb[kb * PLANE + n * TROW + 0  + q * 8];
      short8 a1 = *(short8*)&ldsb[kb * PLANE + n * TROW + 32 + q * 8];
      f32x4 acc = {0.f, 0.f, 0.f, 0.f};
      acc = MFMA_BF16(a0, BF[GRADE[kb]][0], acc, 0, 0, 0);
      acc = MFMA_BF16(a1, BF[GRADE[kb]][1], acc, 0, 0, 0);
      D[kb] = acc;
    }

    const int o = w * 16 + n;
    #pragma unroll
    for (int r = 0; r < 4; ++r) {
      const int t = t0 + 4 * q + r;
      float4* op = (float4*)(out + (size_t)t * 1024 + o * 16);
      op[0] = make_float4(D[0][r],  D[1][r],  D[2][r],  D[3][r]);
      op[1] = make_float4(D[4][r],  D[5][r],  D[6][r],  D[7][r]);
      op[2] = make_float4(D[8][r],  D[9][r],  D[10][r], D[11][r]);
      op[3] = make_float4(D[12][r], D[13][r], D[14][r], D[15][r]);
    }
  }
}

extern "C" void kernel_launch(void* const* d_in, const int* in_sizes, int n_in,
                              void* d_out, int out_size, void* d_ws, size_t ws_size,
                              hipStream_t stream) {
  const float* x   = (const float*)d_in[0];
  const float* ref = (const float*)d_in[1];
  const float* wpx = (const float*)d_in[2];
  const float* wpy = (const float*)d_in[3];
  const float* wjx = (const float*)d_in[4];
  const float* wjy = (const float*)d_in[5];
  const float* wfi = (const float*)d_in[6];

  cast_weights<<<240, 256, 0, stream>>>(wpx, wpy, wjx, wjy, wfi);
  gbl_kernel<<<BN / 16, 256, 0, stream>>>(x, ref, (float*)d_out);
}